// Round 1
// 1153.726 us; speedup vs baseline: 1.0018x; 1.0018x over previous
//
#include <hip/hip_runtime.h>

// ERNN cell on MI355X. Inputs/outputs FLOAT32. Output f32.
// Math: P = V2@V + I;  wxp[t] = x[t]@(W@P) + b@P  (parallel precompute, bf16)
//   per step: s = h_cur + h_prev;  pre = s + s@(P^2 - I) + wxp[t]
//   h_cur = a*(tanh(pre) - h_prev) + (1-a)*h_cur   (K iters, K=1)
// Identity split keeps MFMA operand E = P^2 - I small -> bf16 rounding harmless.
//
// R5 changes (LDS-bandwidth theory):
//  - scan: 16 WGs x 256 threads (4 waves, 64 cols/wave). Each wave re-reads the
//    full 16x256 s-matrix per step regardless of its col count, so 4 waves halve
//    LDS read traffic vs 8 (64KB -> 32KB/step/CU) at identical per-SIMD VALU/MFMA.
//  - S XOR-swizzle: byte ^= parity(row>>2)<<5 spreads write banks of the 4 quads
//    to {0,24,8,16} (was {0,16,0,16} -> 4-way conflict, 4.19M conflict cycles).
//    Reads stay 2-way (free). Swizzle is loop-invariant; p-toggle removed via
//    2-step unroll with literal buffer index.
//  - K==1 fast path: hp==hc -> single state q=2h, lean epilogue.
//  - Et/WPt transposed tables -> vector fragment loads (scan + wxp prologue).

#define HID   256
#define NF    128
#define SEQ   1024
#define SSTR  264    // s LDS row stride in bf16 elems (pad 8; keeps rows 16B-aligned)

typedef __bf16 bf16_t;
typedef __bf16 bf16x8 __attribute__((ext_vector_type(8)));
typedef float  f32x4  __attribute__((ext_vector_type(4)));

__device__ __forceinline__ float fast_tanh(float x) {
    float e = __builtin_amdgcn_exp2f(x * 2.8853900817779268f);
    return 1.0f - 2.0f * __builtin_amdgcn_rcpf(e + 1.0f);
}

// physical byte offset of S element (row,col) = ((row*SSTR+col)*2) ^ (parity(row>>2)<<5)
__device__ __forceinline__ int s_swz(int row) {
    return (((row >> 2) ^ (row >> 3)) & 1) << 5;
}

// ---------- k0: P = V2@V + I (f32) ----------
__global__ void k_P(const float* __restrict__ V2, const float* __restrict__ V,
                    float* __restrict__ P) {
    __shared__ float v2row[64];
    int i = blockIdx.x, j = threadIdx.x;
    if (j < 64) v2row[j] = V2[i * 64 + j];
    __syncthreads();
    float s = (i == j) ? 1.0f : 0.0f;
    #pragma unroll 4
    for (int v = 0; v < 64; ++v) s += v2row[v] * V[v * HID + j];
    P[i * HID + j] = s;
}

// ---------- k1: Et = bf16((P@P - I)^T)  (transposed -> vector B-frag loads) ----------
__global__ void k_E(const float* __restrict__ P, bf16_t* __restrict__ Et) {
    __shared__ float prow[HID];
    int i = blockIdx.x, j = threadIdx.x;
    prow[j] = P[i * HID + j];
    __syncthreads();
    float s = (i == j) ? -1.0f : 0.0f;
    #pragma unroll 4
    for (int k = 0; k < HID; ++k) s += prow[k] * P[k * HID + j];
    Et[(size_t)j * HID + i] = (bf16_t)s;   // Et[col][k] = E[k][col]
}

// ---------- k2: WPt = bf16((W@P)^T), bP = b@P (f32) ----------
__global__ void k_WP(const float* __restrict__ W, const float* __restrict__ b,
                     const float* __restrict__ P,
                     bf16_t* __restrict__ WPt, float* __restrict__ bP) {
    __shared__ float row[HID];
    int i = blockIdx.x, j = threadIdx.x;
    if (i < NF) {
        row[j] = W[i * HID + j];
        __syncthreads();
        float s = 0.f;
        #pragma unroll 4
        for (int k = 0; k < HID; ++k) s += row[k] * P[k * HID + j];
        WPt[(size_t)j * NF + i] = (bf16_t)s;   // WPt[col][k] = (W@P)[k][col]
    } else {
        row[j] = b[j];
        __syncthreads();
        float s = 0.f;
        #pragma unroll 4
        for (int k = 0; k < HID; ++k) s += row[k] * P[k * HID + j];
        bP[j] = s;
    }
}

// ---------- k3: wxp = bf16(x@WP + bP) in 256-thread scan-ready layout ----------
// scan thread tid of WG g at step t reads bf16x8 pairs at
//   wxp + (t*16+g)*4096 + tid*8         (elems e=0..7  = c{0,1} x r)
//   wxp + (t*16+g)*4096 + 2048 + tid*8  (elems e=8..15 = c{2,3} x r)
__global__ __launch_bounds__(256) void k_wxp(const float* __restrict__ x,
                                             const bf16_t* __restrict__ WPt,
                                             const float* __restrict__ bP,
                                             bf16_t* __restrict__ wxp) {
    int tid = threadIdx.x;
    int lane = tid & 63, w = tid >> 6;
    int quad = lane >> 4, m = lane & 15;
    bf16x8 Bf[4][4];
    float bPv[4];
    #pragma unroll
    for (int c = 0; c < 4; ++c) {
        int col = w * 64 + c * 16 + m;
        bPv[c] = bP[col];
        const bf16_t* wp = WPt + (size_t)col * NF + quad * 8;
        #pragma unroll
        for (int kt = 0; kt < 4; ++kt)
            Bf[c][kt] = *(const bf16x8*)(wp + kt * 32);
    }
    for (int i = 0; i < 8; ++i) {
        int tile = blockIdx.x * 8 + i;          // t*16 + g
        int t = tile >> 4, g = tile & 15;
        const float* xp = x + (((size_t)t * 256 + g * 16 + m) * NF + quad * 8);
        f32x4 acc[4];
        #pragma unroll
        for (int c = 0; c < 4; ++c) acc[c] = (f32x4){bPv[c], bPv[c], bPv[c], bPv[c]};
        #pragma unroll
        for (int kt = 0; kt < 4; ++kt) {
            f32x4 xa = *(const f32x4*)(xp + kt * 32);
            f32x4 xb = *(const f32x4*)(xp + kt * 32 + 4);
            bf16x8 aa;
            #pragma unroll
            for (int j = 0; j < 4; ++j) { aa[j] = (bf16_t)xa[j]; aa[4 + j] = (bf16_t)xb[j]; }
            #pragma unroll
            for (int c = 0; c < 4; ++c)
                acc[c] = __builtin_amdgcn_mfma_f32_16x16x32_bf16(aa, Bf[c][kt], acc[c], 0, 0, 0);
        }
        bf16x8 lo, hi;
        #pragma unroll
        for (int c = 0; c < 2; ++c)
            #pragma unroll
            for (int r = 0; r < 4; ++r) {
                lo[c * 4 + r] = (bf16_t)acc[c][r];
                hi[c * 4 + r] = (bf16_t)acc[2 + c][r];
            }
        size_t tb = (size_t)tile * 4096;
        *(bf16x8*)(wxp + tb + tid * 8)        = lo;   // fully coalesced per instr
        *(bf16x8*)(wxp + tb + 2048 + tid * 8) = hi;
    }
}

// ---------- k4: scan with precomputed wxp; 16 WGs x 256 threads ----------
__global__ __launch_bounds__(256, 1) void k_scan_pre(const float* __restrict__ h_in,
                                                     const float* __restrict__ alpha,
                                                     const int* __restrict__ Kp,
                                                     const bf16_t* __restrict__ Et,
                                                     const bf16_t* __restrict__ wxp,
                                                     float* __restrict__ out) {
    __shared__ bf16_t S[2][16 * SSTR];
    int g = blockIdx.x;
    int tid = threadIdx.x;
    int lane = tid & 63, w = tid >> 6, quad = lane >> 4, m = lane & 15;
    int colbase = w * 64 + m;

    // B fragments of E for this wave's 64 cols (4 col-tiles x 8 k-tiles), vector loads
    bf16x8 Ef[32];
    #pragma unroll
    for (int c = 0; c < 4; ++c) {
        const bf16_t* ep = Et + (size_t)(colbase + c * 16) * HID + quad * 8;
        #pragma unroll
        for (int kt = 0; kt < 8; ++kt)
            Ef[c * 8 + kt] = *(const bf16x8*)(ep + kt * 32);
    }

    // swizzled LDS offsets (all loop-invariant; swizzle bit5 never interacts with
    // the +kt*64 read stride, so rd_base hoists cleanly)
    const int rd_base = (m * (SSTR * 2) + quad * 16) ^ s_swz(m);
    int woff[16];
    #pragma unroll
    for (int c = 0; c < 4; ++c)
        #pragma unroll
        for (int r = 0; r < 4; ++r) {
            int row = quad * 4 + r, col = colbase + c * 16;
            woff[c * 4 + r] = ((row * SSTR + col) * 2) ^ s_swz(row);
        }

    float a = alpha[0];
    int K = Kp[0];
    if (K < 1 || K > 64) K = 1;

    float hv[16];
    #pragma unroll
    for (int c = 0; c < 4; ++c)
        #pragma unroll
        for (int r = 0; r < 4; ++r) {
            int e = c * 4 + r;
            int row = quad * 4 + r, col = colbase + c * 16;
            float v = h_in[(g * 16 + row) * HID + col];
            hv[e] = v;
            *(bf16_t*)((char*)&S[0][0] + woff[e]) = (bf16_t)(2.0f * v);
        }
    __syncthreads();

    const bf16_t* wlo = wxp + (size_t)g * 4096 + (size_t)tid * 8;
    const bf16_t* whi = wlo + 2048;
    const long WSTR = 65536;   // elems per timestep (16 tiles * 4096)

    bf16x8 wl = *(const bf16x8*)wlo;
    bf16x8 wh = *(const bf16x8*)whi;

    if (K == 1) {
        // K==1: hp==hc always -> single state q = 2*h.
        // q_new = 2a*tanh(pre) + (1-2a)*q,  pre = acc + q,  h_out = q/2.
        const float A2 = 2.0f * a, B2 = 1.0f - 2.0f * a;
        float q[16];
        #pragma unroll
        for (int e = 0; e < 16; ++e) q[e] = 2.0f * hv[e];

        auto step = [&](int p, int t) {   // p is a literal at both call sites
            int tn = (t + 1 < SEQ) ? t + 1 : t;
            bf16x8 wln = *(const bf16x8*)(wlo + (long)tn * WSTR);
            bf16x8 whn = *(const bf16x8*)(whi + (long)tn * WSTR);
            f32x4 acc[4];
            #pragma unroll
            for (int r = 0; r < 4; ++r) {
                acc[0][r] = (float)wl[r];
                acc[1][r] = (float)wl[4 + r];
                acc[2][r] = (float)wh[r];
                acc[3][r] = (float)wh[4 + r];
            }
            const char* sb = (const char*)&S[p][0];
            #pragma unroll
            for (int kt = 0; kt < 8; ++kt) {
                bf16x8 af = *(const bf16x8*)(sb + rd_base + kt * 64);
                #pragma unroll
                for (int c = 0; c < 4; ++c)
                    acc[c] = __builtin_amdgcn_mfma_f32_16x16x32_bf16(af, Ef[c * 8 + kt], acc[c], 0, 0, 0);
            }
            char* swp = (char*)&S[p ^ 1][0];
            #pragma unroll
            for (int c = 0; c < 4; ++c)
                #pragma unroll
                for (int r = 0; r < 4; ++r) {
                    int e = c * 4 + r;
                    float pre = acc[c][r] + q[e];
                    float T = fast_tanh(pre);
                    float qn = fmaf(A2, T, B2 * q[e]);
                    q[e] = qn;
                    *(bf16_t*)(swp + woff[e]) = (bf16_t)qn;
                }
            __syncthreads();
            wl = wln; wh = whn;
        };
        for (int t = 0; t < SEQ; t += 2) { step(0, t); step(1, t + 1); }

        #pragma unroll
        for (int c = 0; c < 4; ++c)
            #pragma unroll
            for (int r = 0; r < 4; ++r) {
                int row = quad * 4 + r, col = colbase + c * 16;
                out[(g * 16 + row) * HID + col] = 0.5f * q[c * 4 + r];
            }
    } else {
        // general K path (not exercised by the bench; kept correct)
        float hp[16], hc[16], sreg[16];
        #pragma unroll
        for (int e = 0; e < 16; ++e) { hp[e] = hv[e]; hc[e] = hv[e]; sreg[e] = 2.0f * hv[e]; }
        float one_ma = 1.0f - a;
        int p = 0;
        for (int t = 0; t < SEQ; ++t) {
            int tn = (t + 1 < SEQ) ? t + 1 : t;
            bf16x8 wln = *(const bf16x8*)(wlo + (long)tn * WSTR);
            bf16x8 whn = *(const bf16x8*)(whi + (long)tn * WSTR);
            for (int k = 0; k < K; ++k) {
                f32x4 acc[4];
                #pragma unroll
                for (int r = 0; r < 4; ++r) {
                    acc[0][r] = (float)wl[r];
                    acc[1][r] = (float)wl[4 + r];
                    acc[2][r] = (float)wh[r];
                    acc[3][r] = (float)wh[4 + r];
                }
                const char* sb = (const char*)&S[p][0];
                #pragma unroll
                for (int kt = 0; kt < 8; ++kt) {
                    bf16x8 af = *(const bf16x8*)(sb + rd_base + kt * 64);
                    #pragma unroll
                    for (int c = 0; c < 4; ++c)
                        acc[c] = __builtin_amdgcn_mfma_f32_16x16x32_bf16(af, Ef[c * 8 + kt], acc[c], 0, 0, 0);
                }
                bool last = (k == K - 1);
                char* swp = (char*)&S[p ^ 1][0];
                #pragma unroll
                for (int c = 0; c < 4; ++c)
                    #pragma unroll
                    for (int r = 0; r < 4; ++r) {
                        int e = c * 4 + r;
                        float pre = acc[c][r] + sreg[e];
                        float T = fast_tanh(pre);
                        float hn = a * (T - hp[e]) + one_ma * hc[e];
                        float sn;
                        if (last) { hp[e] = hn; hc[e] = hn; sn = 2.0f * hn; }
                        else      { hc[e] = hn; sn = hn + hp[e]; }
                        sreg[e] = sn;
                        *(bf16_t*)(swp + woff[e]) = (bf16_t)sn;
                    }
                p ^= 1;
                __syncthreads();
            }
            wl = wln; wh = whn;
        }
        #pragma unroll
        for (int c = 0; c < 4; ++c)
            #pragma unroll
            for (int r = 0; r < 4; ++r) {
                int row = quad * 4 + r, col = colbase + c * 16;
                out[(g * 16 + row) * HID + col] = hp[c * 4 + r];
            }
    }
}

// ---------- fallback: fused scan (256 threads), wxp workspace not available ----------
__global__ __launch_bounds__(256, 1) void k_scan_fused(const float* __restrict__ h_in,
                                                 const float* __restrict__ alpha,
                                                 const int* __restrict__ Kp,
                                                 const bf16_t* __restrict__ Et,
                                                 const bf16_t* __restrict__ WPt,
                                                 const float* __restrict__ bP,
                                                 const float* __restrict__ x,
                                                 float* __restrict__ out) {
    __shared__ bf16_t S[2][16 * SSTR];
    int g = blockIdx.x;
    int tid = threadIdx.x;
    int lane = tid & 63, w = tid >> 6, quad = lane >> 4, m = lane & 15;
    int colbase = w * 64 + m;
    bf16x8 Ef[32];
    bf16x8 Wf[16];
    float bPv[4];
    #pragma unroll
    for (int c = 0; c < 4; ++c) {
        int col = colbase + c * 16;
        bPv[c] = bP[col];
        const bf16_t* ep = Et + (size_t)col * HID + quad * 8;
        #pragma unroll
        for (int kt = 0; kt < 8; ++kt)
            Ef[c * 8 + kt] = *(const bf16x8*)(ep + kt * 32);
        const bf16_t* wpp = WPt + (size_t)col * NF + quad * 8;
        #pragma unroll
        for (int kt = 0; kt < 4; ++kt)
            Wf[c * 4 + kt] = *(const bf16x8*)(wpp + kt * 32);
    }
    float hp[16], hc[16], sreg[16];
    #pragma unroll
    for (int c = 0; c < 4; ++c)
        #pragma unroll
        for (int r = 0; r < 4; ++r) {
            int e = c * 4 + r;
            int row = quad * 4 + r, col = colbase + c * 16;
            float v = h_in[(g * 16 + row) * HID + col];
            hp[e] = v; hc[e] = v; sreg[e] = 2.0f * v;
            S[0][row * SSTR + col] = (bf16_t)(2.0f * v);
        }
    float a = alpha[0];
    float one_ma = 1.0f - a;
    int K = Kp[0];
    if (K < 1 || K > 64) K = 1;
    __syncthreads();
    const float* xrow = x + ((g * 16 + m) * NF + quad * 8);
    bf16x8 xf[4];
    #pragma unroll
    for (int kt = 0; kt < 4; ++kt) {
        f32x4 xa = *(const f32x4*)(xrow + kt * 32);
        f32x4 xb = *(const f32x4*)(xrow + kt * 32 + 4);
        bf16x8 f;
        #pragma unroll
        for (int j = 0; j < 4; ++j) { f[j] = (bf16_t)xa[j]; f[4 + j] = (bf16_t)xb[j]; }
        xf[kt] = f;
    }
    int p = 0;
    for (int t = 0; t < SEQ; ++t) {
        int tn = (t + 1 < SEQ) ? t + 1 : t;
        const float* xn = xrow + (size_t)tn * (256 * NF);
        bf16x8 xnf[4];
        #pragma unroll
        for (int kt = 0; kt < 4; ++kt) {
            f32x4 xa = *(const f32x4*)(xn + kt * 32);
            f32x4 xb = *(const f32x4*)(xn + kt * 32 + 4);
            bf16x8 f;
            #pragma unroll
            for (int j = 0; j < 4; ++j) { f[j] = (bf16_t)xa[j]; f[4 + j] = (bf16_t)xb[j]; }
            xnf[kt] = f;
        }
        f32x4 wxacc[4];
        #pragma unroll
        for (int c = 0; c < 4; ++c) wxacc[c] = (f32x4){bPv[c], bPv[c], bPv[c], bPv[c]};
        #pragma unroll
        for (int kt = 0; kt < 4; ++kt)
            #pragma unroll
            for (int c = 0; c < 4; ++c)
                wxacc[c] = __builtin_amdgcn_mfma_f32_16x16x32_bf16(xf[kt], Wf[c * 4 + kt], wxacc[c], 0, 0, 0);
        for (int k = 0; k < K; ++k) {
            f32x4 acc[4];
            #pragma unroll
            for (int c = 0; c < 4; ++c) acc[c] = wxacc[c];
            const bf16_t* sbase = &S[p][m * SSTR];
            #pragma unroll
            for (int kt = 0; kt < 8; ++kt) {
                bf16x8 af = *(const bf16x8*)(sbase + kt * 32 + quad * 8);
                #pragma unroll
                for (int c = 0; c < 4; ++c)
                    acc[c] = __builtin_amdgcn_mfma_f32_16x16x32_bf16(af, Ef[c * 8 + kt], acc[c], 0, 0, 0);
            }
            bool last = (k == K - 1);
            #pragma unroll
            for (int c = 0; c < 4; ++c) {
                int col = colbase + c * 16;
                #pragma unroll
                for (int r = 0; r < 4; ++r) {
                    int e = c * 4 + r;
                    int row = quad * 4 + r;
                    float pre = acc[c][r] + sreg[e];
                    float T = fast_tanh(pre);
                    float hn = a * (T - hp[e]) + one_ma * hc[e];
                    float sn;
                    if (last) { hp[e] = hn; hc[e] = hn; sn = 2.0f * hn; }
                    else      { hc[e] = hn; sn = hn + hp[e]; }
                    sreg[e] = sn;
                    S[p ^ 1][row * SSTR + col] = (bf16_t)sn;
                }
            }
            p ^= 1;
            __syncthreads();
        }
        #pragma unroll
        for (int kt = 0; kt < 4; ++kt) xf[kt] = xnf[kt];
    }
    #pragma unroll
    for (int c = 0; c < 4; ++c)
        #pragma unroll
        for (int r = 0; r < 4; ++r) {
            int row = quad * 4 + r, col = colbase + c * 16;
            out[(g * 16 + row) * HID + col] = hp[c * 4 + r];
        }
}

extern "C" void kernel_launch(void* const* d_in, const int* in_sizes, int n_in,
                              void* d_out, int out_size, void* d_ws, size_t ws_size,
                              hipStream_t stream) {
    const float* x     = (const float*)d_in[0];
    const float* h     = (const float*)d_in[1];
    const float* W     = (const float*)d_in[2];
    const float* b     = (const float*)d_in[3];
    const float* V     = (const float*)d_in[4];
    const float* V2    = (const float*)d_in[5];
    const float* alpha = (const float*)d_in[6];
    const int*   Kp    = (const int*)d_in[7];

    char* ws = (char*)d_ws;
    float*  P   = (float*)ws;                     // 256 KB
    bf16_t* Et  = (bf16_t*)(ws + (256u << 10));   // 128 KB (E^T)
    bf16_t* WPt = (bf16_t*)(ws + (384u << 10));   // 64 KB ((W@P)^T)
    float*  bP  = (float*)(ws + (448u << 10));    // 1 KB
    bf16_t* wxp = (bf16_t*)(ws + (512u << 10));   // 128 MB (optional)
    size_t need = (512u << 10) + (size_t)SEQ * 16 * 512 * 8 * sizeof(bf16_t);

    hipLaunchKernelGGL(k_P,  dim3(256), dim3(256), 0, stream, V2, V, P);
    hipLaunchKernelGGL(k_E,  dim3(256), dim3(256), 0, stream, P, Et);
    hipLaunchKernelGGL(k_WP, dim3(129), dim3(256), 0, stream, W, b, P, WPt, bP);
    if (ws_size >= need) {
        hipLaunchKernelGGL(k_wxp, dim3(2048), dim3(256), 0, stream, x, WPt, bP, wxp);
        hipLaunchKernelGGL(k_scan_pre, dim3(16), dim3(256), 0, stream, h, alpha, Kp, Et, wxp, (float*)d_out);
    } else {
        hipLaunchKernelGGL(k_scan_fused, dim3(16), dim3(256), 0, stream, h, alpha, Kp, Et, WPt, bP, x, (float*)d_out);
    }
}

// Round 2
// 1094.682 us; speedup vs baseline: 1.0558x; 1.0539x over previous
//
#include <hip/hip_runtime.h>

// ERNN cell on MI355X. Inputs/outputs FLOAT32. Output f32.
// Math: P = V2@V + I;  wxp[t] = x[t]@(W@P) + b@P  (parallel precompute, bf16)
//   per step: s = h_cur + h_prev;  pre = s + s@(P^2 - I) + wxp[t]
//   h_cur = a*(tanh(pre) - h_prev) + (1-a)*h_cur   (K iters, K=1)
// Identity split keeps MFMA operand E = P^2 - I small -> bf16 rounding harmless.
//
// R6 changes (barrier-drain theory):
//  - R5 (halved LDS traffic + conflicts) was perf-neutral => scan is stall-bound,
//    not LDS/VALU/MFMA-throughput-bound. Diagnosis: __syncthreads emits
//    s_waitcnt vmcnt(0) before s_barrier, draining the per-step wxp global
//    prefetch (~700-900cy L3/HBM latency) onto the critical path every step.
//  - Fix: raw s_barrier + explicit lgkmcnt(0) (LDS writes drained; global loads
//    stay in flight across the barrier; compiler emits counted vmcnt before use).
//    Prefetch deepened to 2 steps (~2 step-times of cover).
//  - MFMA chain split into 2 halves (8 indep 4-deep chains) to cut dep latency.
//  - sched_barrier(0) after s_barrier stops the scheduler hoisting next-step
//    ds_reads above the barrier (rule #18-adjacent hazard).

#define HID   256
#define NF    128
#define SEQ   1024
#define SSTR  264    // s LDS row stride in bf16 elems (pad 8; keeps rows 16B-aligned)

typedef __bf16 bf16_t;
typedef __bf16 bf16x8 __attribute__((ext_vector_type(8)));
typedef float  f32x4  __attribute__((ext_vector_type(4)));

__device__ __forceinline__ float fast_tanh(float x) {
    float e = __builtin_amdgcn_exp2f(x * 2.8853900817779268f);
    return 1.0f - 2.0f * __builtin_amdgcn_rcpf(e + 1.0f);
}

// physical byte offset of S element (row,col) = ((row*SSTR+col)*2) ^ (parity(row>>2)<<5)
__device__ __forceinline__ int s_swz(int row) {
    return (((row >> 2) ^ (row >> 3)) & 1) << 5;
}

// ---------- k0: P = V2@V + I (f32) ----------
__global__ void k_P(const float* __restrict__ V2, const float* __restrict__ V,
                    float* __restrict__ P) {
    __shared__ float v2row[64];
    int i = blockIdx.x, j = threadIdx.x;
    if (j < 64) v2row[j] = V2[i * 64 + j];
    __syncthreads();
    float s = (i == j) ? 1.0f : 0.0f;
    #pragma unroll 4
    for (int v = 0; v < 64; ++v) s += v2row[v] * V[v * HID + j];
    P[i * HID + j] = s;
}

// ---------- k1: Et = bf16((P@P - I)^T)  (transposed -> vector B-frag loads) ----------
__global__ void k_E(const float* __restrict__ P, bf16_t* __restrict__ Et) {
    __shared__ float prow[HID];
    int i = blockIdx.x, j = threadIdx.x;
    prow[j] = P[i * HID + j];
    __syncthreads();
    float s = (i == j) ? -1.0f : 0.0f;
    #pragma unroll 4
    for (int k = 0; k < HID; ++k) s += prow[k] * P[k * HID + j];
    Et[(size_t)j * HID + i] = (bf16_t)s;   // Et[col][k] = E[k][col]
}

// ---------- k2: WPt = bf16((W@P)^T), bP = b@P (f32) ----------
__global__ void k_WP(const float* __restrict__ W, const float* __restrict__ b,
                     const float* __restrict__ P,
                     bf16_t* __restrict__ WPt, float* __restrict__ bP) {
    __shared__ float row[HID];
    int i = blockIdx.x, j = threadIdx.x;
    if (i < NF) {
        row[j] = W[i * HID + j];
        __syncthreads();
        float s = 0.f;
        #pragma unroll 4
        for (int k = 0; k < HID; ++k) s += row[k] * P[k * HID + j];
        WPt[(size_t)j * NF + i] = (bf16_t)s;   // WPt[col][k] = (W@P)[k][col]
    } else {
        row[j] = b[j];
        __syncthreads();
        float s = 0.f;
        #pragma unroll 4
        for (int k = 0; k < HID; ++k) s += row[k] * P[k * HID + j];
        bP[j] = s;
    }
}

// ---------- k3: wxp = bf16(x@WP + bP) in 256-thread scan-ready layout ----------
// scan thread tid of WG g at step t reads bf16x8 pairs at
//   wxp + (t*16+g)*4096 + tid*8         (elems e=0..7  = c{0,1} x r)
//   wxp + (t*16+g)*4096 + 2048 + tid*8  (elems e=8..15 = c{2,3} x r)
__global__ __launch_bounds__(256) void k_wxp(const float* __restrict__ x,
                                             const bf16_t* __restrict__ WPt,
                                             const float* __restrict__ bP,
                                             bf16_t* __restrict__ wxp) {
    int tid = threadIdx.x;
    int lane = tid & 63, w = tid >> 6;
    int quad = lane >> 4, m = lane & 15;
    bf16x8 Bf[4][4];
    float bPv[4];
    #pragma unroll
    for (int c = 0; c < 4; ++c) {
        int col = w * 64 + c * 16 + m;
        bPv[c] = bP[col];
        const bf16_t* wp = WPt + (size_t)col * NF + quad * 8;
        #pragma unroll
        for (int kt = 0; kt < 4; ++kt)
            Bf[c][kt] = *(const bf16x8*)(wp + kt * 32);
    }
    for (int i = 0; i < 8; ++i) {
        int tile = blockIdx.x * 8 + i;          // t*16 + g
        int t = tile >> 4, g = tile & 15;
        const float* xp = x + (((size_t)t * 256 + g * 16 + m) * NF + quad * 8);
        f32x4 acc[4];
        #pragma unroll
        for (int c = 0; c < 4; ++c) acc[c] = (f32x4){bPv[c], bPv[c], bPv[c], bPv[c]};
        #pragma unroll
        for (int kt = 0; kt < 4; ++kt) {
            f32x4 xa = *(const f32x4*)(xp + kt * 32);
            f32x4 xb = *(const f32x4*)(xp + kt * 32 + 4);
            bf16x8 aa;
            #pragma unroll
            for (int j = 0; j < 4; ++j) { aa[j] = (bf16_t)xa[j]; aa[4 + j] = (bf16_t)xb[j]; }
            #pragma unroll
            for (int c = 0; c < 4; ++c)
                acc[c] = __builtin_amdgcn_mfma_f32_16x16x32_bf16(aa, Bf[c][kt], acc[c], 0, 0, 0);
        }
        bf16x8 lo, hi;
        #pragma unroll
        for (int c = 0; c < 2; ++c)
            #pragma unroll
            for (int r = 0; r < 4; ++r) {
                lo[c * 4 + r] = (bf16_t)acc[c][r];
                hi[c * 4 + r] = (bf16_t)acc[2 + c][r];
            }
        size_t tb = (size_t)tile * 4096;
        *(bf16x8*)(wxp + tb + tid * 8)        = lo;   // fully coalesced per instr
        *(bf16x8*)(wxp + tb + 2048 + tid * 8) = hi;
    }
}

// ---------- k4: scan with precomputed wxp; 16 WGs x 256 threads ----------
__global__ __launch_bounds__(256, 1) void k_scan_pre(const float* __restrict__ h_in,
                                                     const float* __restrict__ alpha,
                                                     const int* __restrict__ Kp,
                                                     const bf16_t* __restrict__ Et,
                                                     const bf16_t* __restrict__ wxp,
                                                     float* __restrict__ out) {
    __shared__ bf16_t S[2][16 * SSTR];
    int g = blockIdx.x;
    int tid = threadIdx.x;
    int lane = tid & 63, w = tid >> 6, quad = lane >> 4, m = lane & 15;
    int colbase = w * 64 + m;

    // B fragments of E for this wave's 64 cols (4 col-tiles x 8 k-tiles), vector loads
    bf16x8 Ef[32];
    #pragma unroll
    for (int c = 0; c < 4; ++c) {
        const bf16_t* ep = Et + (size_t)(colbase + c * 16) * HID + quad * 8;
        #pragma unroll
        for (int kt = 0; kt < 8; ++kt)
            Ef[c * 8 + kt] = *(const bf16x8*)(ep + kt * 32);
    }

    // swizzled LDS offsets (all loop-invariant; swizzle bit5 never interacts with
    // the +kt*64 read stride, so rd_base hoists cleanly)
    const int rd_base = (m * (SSTR * 2) + quad * 16) ^ s_swz(m);
    int woff[16];
    #pragma unroll
    for (int c = 0; c < 4; ++c)
        #pragma unroll
        for (int r = 0; r < 4; ++r) {
            int row = quad * 4 + r, col = colbase + c * 16;
            woff[c * 4 + r] = ((row * SSTR + col) * 2) ^ s_swz(row);
        }

    float a = alpha[0];
    int K = Kp[0];
    if (K < 1 || K > 64) K = 1;

    float hv[16];
    #pragma unroll
    for (int c = 0; c < 4; ++c)
        #pragma unroll
        for (int r = 0; r < 4; ++r) {
            int e = c * 4 + r;
            int row = quad * 4 + r, col = colbase + c * 16;
            float v = h_in[(g * 16 + row) * HID + col];
            hv[e] = v;
            *(bf16_t*)((char*)&S[0][0] + woff[e]) = (bf16_t)(2.0f * v);
        }
    __syncthreads();

    const bf16_t* wlo = wxp + (size_t)g * 4096 + (size_t)tid * 8;
    const bf16_t* whi = wlo + 2048;
    const long WSTR = 65536;   // elems per timestep (16 tiles * 4096)

    if (K == 1) {
        // K==1: hp==hc always -> single state q = 2*h.
        // q_new = 2a*tanh(pre) + (1-2a)*q,  pre = acc + q,  h_out = q/2.
        const float A2 = 2.0f * a, B2 = 1.0f - 2.0f * a;
        float q[16];
        #pragma unroll
        for (int e = 0; e < 16; ++e) q[e] = 2.0f * hv[e];

        // 2-deep wx prefetch: loads stay in flight ACROSS barriers (raw s_barrier,
        // no vmcnt drain). Compiler inserts counted vmcnt before each use.
        bf16x8 wlA = *(const bf16x8*)(wlo);
        bf16x8 whA = *(const bf16x8*)(whi);
        bf16x8 wlB = *(const bf16x8*)(wlo + WSTR);
        bf16x8 whB = *(const bf16x8*)(whi + WSTR);

        auto step = [&](int p, int t) {   // p is a literal at both call sites
            int tpf = (t + 2 < SEQ) ? t + 2 : SEQ - 1;
            bf16x8 wlC = *(const bf16x8*)(wlo + (long)tpf * WSTR);
            bf16x8 whC = *(const bf16x8*)(whi + (long)tpf * WSTR);

            f32x4 acc[4], accb[4];
            #pragma unroll
            for (int r = 0; r < 4; ++r) {
                acc[0][r] = (float)wlA[r];
                acc[1][r] = (float)wlA[4 + r];
                acc[2][r] = (float)whA[r];
                acc[3][r] = (float)whA[4 + r];
            }
            #pragma unroll
            for (int c = 0; c < 4; ++c) accb[c] = (f32x4){0.f, 0.f, 0.f, 0.f};

            const char* sb = (const char*)&S[p][0];
            bf16x8 af[8];
            #pragma unroll
            for (int kt = 0; kt < 8; ++kt)
                af[kt] = *(const bf16x8*)(sb + rd_base + kt * 64);
            // two 4-deep chains per col-tile (8 indep chains total)
            #pragma unroll
            for (int kt = 0; kt < 4; ++kt)
                #pragma unroll
                for (int c = 0; c < 4; ++c)
                    acc[c] = __builtin_amdgcn_mfma_f32_16x16x32_bf16(af[kt], Ef[c * 8 + kt], acc[c], 0, 0, 0);
            #pragma unroll
            for (int kt = 4; kt < 8; ++kt)
                #pragma unroll
                for (int c = 0; c < 4; ++c)
                    accb[c] = __builtin_amdgcn_mfma_f32_16x16x32_bf16(af[kt], Ef[c * 8 + kt], accb[c], 0, 0, 0);

            char* swp = (char*)&S[p ^ 1][0];
            #pragma unroll
            for (int c = 0; c < 4; ++c)
                #pragma unroll
                for (int r = 0; r < 4; ++r) {
                    int e = c * 4 + r;
                    float pre = (acc[c][r] + accb[c][r]) + q[e];
                    float T = fast_tanh(pre);
                    float qn = fmaf(A2, T, B2 * q[e]);
                    q[e] = qn;
                    *(bf16_t*)(swp + woff[e]) = (bf16_t)qn;
                }
            // drain LDS writes only; global prefetches remain in flight
            asm volatile("s_waitcnt lgkmcnt(0)" ::: "memory");
            __builtin_amdgcn_s_barrier();
            __builtin_amdgcn_sched_barrier(0);
            wlA = wlB; whA = whB; wlB = wlC; whB = whC;
        };
        for (int t = 0; t < SEQ; t += 2) { step(0, t); step(1, t + 1); }

        #pragma unroll
        for (int c = 0; c < 4; ++c)
            #pragma unroll
            for (int r = 0; r < 4; ++r) {
                int row = quad * 4 + r, col = colbase + c * 16;
                out[(g * 16 + row) * HID + col] = 0.5f * q[c * 4 + r];
            }
    } else {
        // general K path (not exercised by the bench; kept correct)
        float hp[16], hc[16], sreg[16];
        #pragma unroll
        for (int e = 0; e < 16; ++e) { hp[e] = hv[e]; hc[e] = hv[e]; sreg[e] = 2.0f * hv[e]; }
        float one_ma = 1.0f - a;
        bf16x8 wl = *(const bf16x8*)(wlo);
        bf16x8 wh = *(const bf16x8*)(whi);
        int p = 0;
        for (int t = 0; t < SEQ; ++t) {
            int tn = (t + 1 < SEQ) ? t + 1 : t;
            bf16x8 wln = *(const bf16x8*)(wlo + (long)tn * WSTR);
            bf16x8 whn = *(const bf16x8*)(whi + (long)tn * WSTR);
            for (int k = 0; k < K; ++k) {
                f32x4 acc[4];
                #pragma unroll
                for (int r = 0; r < 4; ++r) {
                    acc[0][r] = (float)wl[r];
                    acc[1][r] = (float)wl[4 + r];
                    acc[2][r] = (float)wh[r];
                    acc[3][r] = (float)wh[4 + r];
                }
                const char* sb = (const char*)&S[p][0];
                #pragma unroll
                for (int kt = 0; kt < 8; ++kt) {
                    bf16x8 af = *(const bf16x8*)(sb + rd_base + kt * 64);
                    #pragma unroll
                    for (int c = 0; c < 4; ++c)
                        acc[c] = __builtin_amdgcn_mfma_f32_16x16x32_bf16(af, Ef[c * 8 + kt], acc[c], 0, 0, 0);
                }
                bool last = (k == K - 1);
                char* swp = (char*)&S[p ^ 1][0];
                #pragma unroll
                for (int c = 0; c < 4; ++c)
                    #pragma unroll
                    for (int r = 0; r < 4; ++r) {
                        int e = c * 4 + r;
                        float pre = acc[c][r] + sreg[e];
                        float T = fast_tanh(pre);
                        float hn = a * (T - hp[e]) + one_ma * hc[e];
                        float sn;
                        if (last) { hp[e] = hn; hc[e] = hn; sn = 2.0f * hn; }
                        else      { hc[e] = hn; sn = hn + hp[e]; }
                        sreg[e] = sn;
                        *(bf16_t*)(swp + woff[e]) = (bf16_t)sn;
                    }
                p ^= 1;
                __syncthreads();
            }
            wl = wln; wh = whn;
        }
        #pragma unroll
        for (int c = 0; c < 4; ++c)
            #pragma unroll
            for (int r = 0; r < 4; ++r) {
                int row = quad * 4 + r, col = colbase + c * 16;
                out[(g * 16 + row) * HID + col] = hp[c * 4 + r];
            }
    }
}

// ---------- fallback: fused scan (256 threads), wxp workspace not available ----------
__global__ __launch_bounds__(256, 1) void k_scan_fused(const float* __restrict__ h_in,
                                                 const float* __restrict__ alpha,
                                                 const int* __restrict__ Kp,
                                                 const bf16_t* __restrict__ Et,
                                                 const bf16_t* __restrict__ WPt,
                                                 const float* __restrict__ bP,
                                                 const float* __restrict__ x,
                                                 float* __restrict__ out) {
    __shared__ bf16_t S[2][16 * SSTR];
    int g = blockIdx.x;
    int tid = threadIdx.x;
    int lane = tid & 63, w = tid >> 6, quad = lane >> 4, m = lane & 15;
    int colbase = w * 64 + m;
    bf16x8 Ef[32];
    bf16x8 Wf[16];
    float bPv[4];
    #pragma unroll
    for (int c = 0; c < 4; ++c) {
        int col = colbase + c * 16;
        bPv[c] = bP[col];
        const bf16_t* ep = Et + (size_t)col * HID + quad * 8;
        #pragma unroll
        for (int kt = 0; kt < 8; ++kt)
            Ef[c * 8 + kt] = *(const bf16x8*)(ep + kt * 32);
        const bf16_t* wpp = WPt + (size_t)col * NF + quad * 8;
        #pragma unroll
        for (int kt = 0; kt < 4; ++kt)
            Wf[c * 4 + kt] = *(const bf16x8*)(wpp + kt * 32);
    }
    float hp[16], hc[16], sreg[16];
    #pragma unroll
    for (int c = 0; c < 4; ++c)
        #pragma unroll
        for (int r = 0; r < 4; ++r) {
            int e = c * 4 + r;
            int row = quad * 4 + r, col = colbase + c * 16;
            float v = h_in[(g * 16 + row) * HID + col];
            hp[e] = v; hc[e] = v; sreg[e] = 2.0f * v;
            S[0][row * SSTR + col] = (bf16_t)(2.0f * v);
        }
    float a = alpha[0];
    float one_ma = 1.0f - a;
    int K = Kp[0];
    if (K < 1 || K > 64) K = 1;
    __syncthreads();
    const float* xrow = x + ((g * 16 + m) * NF + quad * 8);
    bf16x8 xf[4];
    #pragma unroll
    for (int kt = 0; kt < 4; ++kt) {
        f32x4 xa = *(const f32x4*)(xrow + kt * 32);
        f32x4 xb = *(const f32x4*)(xrow + kt * 32 + 4);
        bf16x8 f;
        #pragma unroll
        for (int j = 0; j < 4; ++j) { f[j] = (bf16_t)xa[j]; f[4 + j] = (bf16_t)xb[j]; }
        xf[kt] = f;
    }
    int p = 0;
    for (int t = 0; t < SEQ; ++t) {
        int tn = (t + 1 < SEQ) ? t + 1 : t;
        const float* xn = xrow + (size_t)tn * (256 * NF);
        bf16x8 xnf[4];
        #pragma unroll
        for (int kt = 0; kt < 4; ++kt) {
            f32x4 xa = *(const f32x4*)(xn + kt * 32);
            f32x4 xb = *(const f32x4*)(xn + kt * 32 + 4);
            bf16x8 f;
            #pragma unroll
            for (int j = 0; j < 4; ++j) { f[j] = (bf16_t)xa[j]; f[4 + j] = (bf16_t)xb[j]; }
            xnf[kt] = f;
        }
        f32x4 wxacc[4];
        #pragma unroll
        for (int c = 0; c < 4; ++c) wxacc[c] = (f32x4){bPv[c], bPv[c], bPv[c], bPv[c]};
        #pragma unroll
        for (int kt = 0; kt < 4; ++kt)
            #pragma unroll
            for (int c = 0; c < 4; ++c)
                wxacc[c] = __builtin_amdgcn_mfma_f32_16x16x32_bf16(xf[kt], Wf[c * 4 + kt], wxacc[c], 0, 0, 0);
        for (int k = 0; k < K; ++k) {
            f32x4 acc[4];
            #pragma unroll
            for (int c = 0; c < 4; ++c) acc[c] = wxacc[c];
            const bf16_t* sbase = &S[p][m * SSTR];
            #pragma unroll
            for (int kt = 0; kt < 8; ++kt) {
                bf16x8 af = *(const bf16x8*)(sbase + kt * 32 + quad * 8);
                #pragma unroll
                for (int c = 0; c < 4; ++c)
                    acc[c] = __builtin_amdgcn_mfma_f32_16x16x32_bf16(af, Ef[c * 8 + kt], acc[c], 0, 0, 0);
            }
            bool last = (k == K - 1);
            #pragma unroll
            for (int c = 0; c < 4; ++c) {
                int col = colbase + c * 16;
                #pragma unroll
                for (int r = 0; r < 4; ++r) {
                    int e = c * 4 + r;
                    int row = quad * 4 + r;
                    float pre = acc[c][r] + sreg[e];
                    float T = fast_tanh(pre);
                    float hn = a * (T - hp[e]) + one_ma * hc[e];
                    float sn;
                    if (last) { hp[e] = hn; hc[e] = hn; sn = 2.0f * hn; }
                    else      { hc[e] = hn; sn = hn + hp[e]; }
                    sreg[e] = sn;
                    S[p ^ 1][row * SSTR + col] = (bf16_t)sn;
                }
            }
            p ^= 1;
            __syncthreads();
        }
        #pragma unroll
        for (int kt = 0; kt < 4; ++kt) xf[kt] = xnf[kt];
    }
    #pragma unroll
    for (int c = 0; c < 4; ++c)
        #pragma unroll
        for (int r = 0; r < 4; ++r) {
            int row = quad * 4 + r, col = colbase + c * 16;
            out[(g * 16 + row) * HID + col] = hp[c * 4 + r];
        }
}

extern "C" void kernel_launch(void* const* d_in, const int* in_sizes, int n_in,
                              void* d_out, int out_size, void* d_ws, size_t ws_size,
                              hipStream_t stream) {
    const float* x     = (const float*)d_in[0];
    const float* h     = (const float*)d_in[1];
    const float* W     = (const float*)d_in[2];
    const float* b     = (const float*)d_in[3];
    const float* V     = (const float*)d_in[4];
    const float* V2    = (const float*)d_in[5];
    const float* alpha = (const float*)d_in[6];
    const int*   Kp    = (const int*)d_in[7];

    char* ws = (char*)d_ws;
    float*  P   = (float*)ws;                     // 256 KB
    bf16_t* Et  = (bf16_t*)(ws + (256u << 10));   // 128 KB (E^T)
    bf16_t* WPt = (bf16_t*)(ws + (384u << 10));   // 64 KB ((W@P)^T)
    float*  bP  = (float*)(ws + (448u << 10));    // 1 KB
    bf16_t* wxp = (bf16_t*)(ws + (512u << 10));   // 128 MB (optional)
    size_t need = (512u << 10) + (size_t)SEQ * 16 * 512 * 8 * sizeof(bf16_t);

    hipLaunchKernelGGL(k_P,  dim3(256), dim3(256), 0, stream, V2, V, P);
    hipLaunchKernelGGL(k_E,  dim3(256), dim3(256), 0, stream, P, Et);
    hipLaunchKernelGGL(k_WP, dim3(129), dim3(256), 0, stream, W, b, P, WPt, bP);
    if (ws_size >= need) {
        hipLaunchKernelGGL(k_wxp, dim3(2048), dim3(256), 0, stream, x, WPt, bP, wxp);
        hipLaunchKernelGGL(k_scan_pre, dim3(16), dim3(256), 0, stream, h, alpha, Kp, Et, wxp, (float*)d_out);
    } else {
        hipLaunchKernelGGL(k_scan_fused, dim3(16), dim3(256), 0, stream, h, alpha, Kp, Et, WPt, bP, x, (float*)d_out);
    }
}